// Round 8
// baseline (288.508 us; speedup 1.0000x reference)
//
#include <hip/hip_runtime.h>

#define TT 256
#define BB 32
#define NN 128
#define HH 128
#define HSTR 136  // fp16 elems; 272B rows -> 16B-aligned b128 frag reads

typedef __attribute__((ext_vector_type(8))) _Float16 half8;
typedef __attribute__((ext_vector_type(4))) float f32x4;

#define L2E 1.4426950408889634f   // log2(e)
#define C2L2E 2.8853900817779268f // 2*log2(e)

__device__ __forceinline__ float frcp(float x) { return __builtin_amdgcn_rcpf(x); }
__device__ __forceinline__ float fexp2(float x) { return __builtin_amdgcn_exp2f(x); }
__device__ __forceinline__ float flog2(float x) { return __builtin_amdgcn_logf(x); }

// softplus(a*z)/a with a' = a*log2e pre-scaled:  log2(1+2^(a'*z)) / a'
__device__ __forceinline__ float head_out(float gp, float apr, float zz) {
    float zp = apr * zz;
    float sp = fmaxf(zp, 0.f) + flog2(1.f + fexp2(-fabsf(zp)));
    return gp * sp * frcp(apr);
}

// Block: 512 threads = 8 waves, 16 sequences (batch b, neurons n0..n0+15).
// Wave w owns gate columns for units u = w*16 + (lane&15); thread-local i,f,g,o.
// Weights pre-scaled by log2e (2*log2e for g-gate); cell state c scaled by
// 2*log2e so every exponential is a bare v_exp_f32. Window schedule exposes
// MFMA/trans overlap: ext MFMAs (no LDS dep) -> h reads -> acc5 chain ->
// gate pair (i,f) -> early exp2(i,f) issued UNDER gate pair (g,o) -> head NL
// -> core NL remainder -> h write -> barrier.
__global__ __launch_bounds__(512, 1) void lstm_kernel(
    const float* __restrict__ in, const float* __restrict__ W_ih,
    const float* __restrict__ b_ih, const float* __restrict__ W_hh,
    const float* __restrict__ b_hh, const float* __restrict__ Wl,
    const float* __restrict__ bl, const float* __restrict__ W1,
    const float* __restrict__ b1, const float* __restrict__ W2,
    const float* __restrict__ b2, float* __restrict__ out)
{
    __shared__ __align__(16) _Float16 h_f16[2][16 * HSTR];
    __shared__ __align__(16) float x_lds[TT * 16];
    __shared__ __align__(16) float out_stage[TT * 16];

    const int tid = threadIdx.x;
    const int w = tid >> 6, l = tid & 63;
    const int lrow = l & 15, lkhi = l >> 4;
    const int u = w * 16 + lrow;
    const int bid = blockIdx.x;
    // XCD-aware map: blocks sharing batch-row b (and output lines) -> same XCD
    const int b = bid & 31, n0 = (bid >> 5) << 4;

    const float sg[4] = {L2E, L2E, C2L2E, L2E};  // per-gate exp2 prescale

    // ---- stage x ----
    for (int i = tid; i < TT * 16; i += 512) {
        int t = i >> 4, j = i & 15;
        x_lds[i] = in[(t * BB + b) * NN + n0 + j];
    }

    // ---- W_hh.T fragments, fp16 RNE, pre-scaled, register resident ----
    half8 wh[4][4];
#pragma unroll
    for (int g = 0; g < 4; ++g)
#pragma unroll
        for (int kt = 0; kt < 4; ++kt) {
            const float* src = W_hh + (g * HH + u) * HH + kt * 32 + lkhi * 8;
            half8 hh;
#pragma unroll
            for (int i = 0; i < 8; ++i) hh[i] = (_Float16)(src[i] * sg[g]);
            wh[g][kt] = hh;
        }

    // ---- ext tile B-frags [wx,wo] (pre-scaled) + bias quads (fp32, exact) ----
    half8 bext[4] = {};
    f32x4 bs4[4];
#pragma unroll
    for (int g = 0; g < 4; ++g) {
        int j = g * HH + u;
        float bsv = (b_ih[j] + b_hh[j]) * sg[g];
        bs4[g] = (f32x4){bsv, bsv, bsv, bsv};
        if (l < 16) {
            bext[g][0] = (_Float16)(W_ih[2 * j] * sg[g]);
            bext[g][1] = (_Float16)(W_ih[2 * j + 1] * sg[g]);
        }
    }

    // ---- Wl fragments (rows >=3 zero; alpha row *L2E), fp16, all waves ----
    half8 wlv[4] = {};
    const float wlsc = (lrow == 1) ? L2E : 1.f;
#pragma unroll
    for (int kt = 0; kt < 4; ++kt)
#pragma unroll
        for (int i = 0; i < 8; ++i) {
            float f = (lrow < 3) ? Wl[lrow * HH + kt * 32 + lkhi * 8 + i] * wlsc : 0.f;
            wlv[kt][i] = (_Float16)f;
        }
    f32x4 blv;
#pragma unroll
    for (int r = 0; r < 4; ++r) {
        int row = lkhi * 4 + r;
        blv[r] = (row < 3) ? bl[row] * ((row == 1) ? L2E : 1.f) : 0.f;
    }

    // ---- per-neuron affine MLP coeffs + t=0 output + t=1 ext prep ----
    float An = 0.f, Cn = 0.f;
    float xv = 0.f;            // x(t) carried across windows (lanes<16)
    half8 aext = {};           // ext A-frag for the upcoming window
    if (l < 16) {
        int n = n0 + l;
#pragma unroll
        for (int k = 0; k < 10; ++k) {
            An = fmaf(W1[n * 10 + k], W2[n * 10 + k], An);
            Cn = fmaf(b1[n * 10 + k], W2[n * 10 + k], Cn);
        }
        Cn += b2[n];
        float x0 = in[b * NN + n0 + l];
        float o0 = head_out(1.f, L2E, fmaf(x0, An, Cn) - 1.f);
        if (w == 0) out_stage[l] = o0;
        xv = in[(BB + b) * NN + n0 + l];   // x(1)
        aext[0] = (_Float16)xv;
        aext[1] = (_Float16)o0;
    }

    for (int i = tid; i < 16 * HSTR; i += 512) {
        h_f16[0][i] = (_Float16)0.f;
        h_f16[1][i] = (_Float16)0.f;
    }
    float c[4] = {0.f, 0.f, 0.f, 0.f};  // scaled by 2*log2e
    __syncthreads();

#pragma unroll 2
    for (int t = 1; t < TT; ++t) {
        const int p = (t - 1) & 1;

        // ---- h_{t-1} fragment reads issued first (latency ~120cy) ----
        half8 ah[4];
#pragma unroll
        for (int kt = 0; kt < 4; ++kt)
            ah[kt] = *(const half8*)(&h_f16[p][lrow * HSTR + kt * 32 + lkhi * 8]);

        // ---- ext MFMAs: no LDS dependency, fire under ds_read latency ----
        f32x4 acc[4];
#pragma unroll
        for (int g = 0; g < 4; ++g)
            acc[g] = __builtin_amdgcn_mfma_f32_16x16x32_f16(aext, bext[g], bs4[g], 0, 0, 0);

        // ---- acc5 chain early (longest dependent chain) ----
        f32x4 acc5 = __builtin_amdgcn_mfma_f32_16x16x32_f16(wlv[0], ah[0], blv, 0, 0, 0);
#pragma unroll
        for (int kt = 1; kt < 4; ++kt)
            acc5 = __builtin_amdgcn_mfma_f32_16x16x32_f16(wlv[kt], ah[kt], acc5, 0, 0, 0);

        // ---- gate pair (i,f): 8 MFMAs, accs complete early ----
#pragma unroll
        for (int kt = 0; kt < 4; ++kt) {
            acc[0] = __builtin_amdgcn_mfma_f32_16x16x32_f16(ah[kt], wh[0][kt], acc[0], 0, 0, 0);
            acc[1] = __builtin_amdgcn_mfma_f32_16x16x32_f16(ah[kt], wh[1][kt], acc[1], 0, 0, 0);
        }

        // ---- early NL: exp2 for i,f — co-issues under (g,o) MFMAs below ----
        float ei[4], ef[4];
#pragma unroll
        for (int r = 0; r < 4; ++r) {
            ei[r] = fexp2(-acc[0][r]);
            ef[r] = fexp2(-acc[1][r]);
        }

        // ---- gate pair (g,o): 8 MFMAs ----
#pragma unroll
        for (int kt = 0; kt < 4; ++kt) {
            acc[2] = __builtin_amdgcn_mfma_f32_16x16x32_f16(ah[kt], wh[2][kt], acc[2], 0, 0, 0);
            acc[3] = __builtin_amdgcn_mfma_f32_16x16x32_f16(ah[kt], wh[3][kt], acc[3], 0, 0, 0);
        }

        // ---- head + next-window prep (lanes<16): overlaps (g,o) MFMAs ----
        if (l < 16) {
            float gp = acc5[0], apr = acc5[1], tp = acc5[2];
            if (t == 1) { gp = 1.f; apr = L2E; tp = 1.f; }
            float ol = fmaf(xv, An, Cn);
            float o = head_out(gp, apr, ol - tp);
            if (w == 0) out_stage[t * 16 + l] = o;
            int tn = (t < TT - 1) ? t + 1 : t;
            xv = x_lds[tn * 16 + l];          // prefetch x(t+1)
            aext[0] = (_Float16)xv;
            aext[1] = (_Float16)o;            // out_t
        }

        // ---- core NL remainder (ei,ef precomputed) ----
#pragma unroll
        for (int r = 0; r < 4; ++r) {
            float eg = fminf(fexp2(-acc[2][r]), 1e30f);
            float eo = fexp2(-acc[3][r]);
            float Dig = (1.f + ei[r]) * (1.f + eg);
            float num = fmaf(-C2L2E, eg, C2L2E);     // 2L2E*(1-eg)
            float fe1 = 1.f + ef[r];
            float numer = fmaf(c[r], Dig, num * fe1);
            c[r] = numer * frcp(fe1 * Dig);          // c scaled by 2L2E
            float ec = fminf(fexp2(-c[r]), 1e30f);
            float hv = (1.f - ec) * frcp((1.f + eo) * (1.f + ec));
            h_f16[p ^ 1][(lkhi * 4 + r) * HSTR + u] = (_Float16)hv;
        }

        __syncthreads();  // h_t visible for step t+1
    }

    // ---- flush staged outputs: coalesced full-line writes ----
#pragma unroll
    for (int i = 0; i < 2; ++i) {
        int idx = tid + i * 512;  // 0..1023 vec4s
        int t = idx >> 2;
        int j4 = (idx & 3) << 2;
        f32x4 v = *(const f32x4*)(out_stage + t * 16 + j4);
        *(f32x4*)(out + (t * BB + b) * NN + n0 + j4) = v;
    }
}

extern "C" void kernel_launch(void* const* d_in, const int* in_sizes, int n_in,
                              void* d_out, int out_size, void* d_ws, size_t ws_size,
                              hipStream_t stream) {
    const float* in   = (const float*)d_in[0];
    const float* W_ih = (const float*)d_in[1];
    const float* b_ih = (const float*)d_in[2];
    const float* W_hh = (const float*)d_in[3];
    const float* b_hh = (const float*)d_in[4];
    const float* Wl   = (const float*)d_in[5];
    const float* bl   = (const float*)d_in[6];
    const float* W1   = (const float*)d_in[7];
    const float* b1   = (const float*)d_in[8];
    const float* W2   = (const float*)d_in[9];
    const float* b2   = (const float*)d_in[10];
    float* out = (float*)d_out;

    lstm_kernel<<<dim3(256), dim3(512), 0, stream>>>(
        in, W_ih, b_ih, W_hh, b_hh, Wl, bl, W1, b1, W2, b2, out);
}